// Round 11
// baseline (177.692 us; speedup 1.0000x reference)
//
#include <hip/hip_runtime.h>
#include <hip/hip_bf16.h>
#include <cstdint>

typedef __bf16 bf16;
typedef __attribute__((ext_vector_type(8))) __bf16 bf16x8;
typedef __attribute__((ext_vector_type(4))) __bf16 bf16x4;
typedef __attribute__((ext_vector_type(2))) __bf16 bf16x2;
typedef __attribute__((ext_vector_type(4))) float f32x4;

#define CEXP 0.1803368801111244f  // (1/8) * log2(e), folded into Q

// ---------------- prep: weight transposes only ---------------------------
__global__ __launch_bounds__(256) void prep_k(const float* __restrict__ Wqkv,
                                              const float* __restrict__ Wout,
                                              bf16* __restrict__ WqkvT,
                                              bf16* __restrict__ WoutT) {
  __shared__ bf16 t[32][33];
  const int z = blockIdx.z;
  const float* src;
  bf16* dst;
  int R, C;
  if (z == 0) {
    src = Wqkv; dst = WqkvT; R = 512; C = 1536;
  } else {
    if (blockIdx.x >= 16) return;  // block-uniform exit (before any barrier)
    src = Wout; dst = WoutT; R = 512; C = 512;
  }
  const int c0 = blockIdx.x * 32, r0 = blockIdx.y * 32;
  const int tx = threadIdx.x, ty = threadIdx.y;
#pragma unroll
  for (int i = 0; i < 4; ++i)
    t[ty + i * 8][tx] = (bf16)src[(size_t)(r0 + ty + i * 8) * C + c0 + tx];
  __syncthreads();
#pragma unroll
  for (int i = 0; i < 4; ++i)
    dst[(size_t)(c0 + ty + i * 8) * R + r0 + tx] = t[tx][ty + i * 8];
}

// swizzle for As column blocks: involution, covers all wave-varying n bits
__device__ __forceinline__ int swz(int n) { return ((n >> 2) ^ (n >> 5)) & 7; }

// ---------------- GEMM1: qkv = x^T @ Wqkv + b, scatter into Q/K/V --------
// A staged via LDS transpose (packed bf16x2 swizzled writes); B-fragments
// load directly from global (WqkvT L2-resident, K-contiguous, 16B-aligned).
// Barrier structure identical to the round-9 known-good kernel.
__global__ __launch_bounds__(256) void gemm_qkv(const float* __restrict__ x,
                                                const bf16* __restrict__ WqkvT,
                                                const float* __restrict__ bqkv,
                                                bf16* __restrict__ Qb,
                                                bf16* __restrict__ Kb,
                                                bf16* __restrict__ Vb) {
  __shared__ bf16 As[128 * 72];  // [n][c-swizzled blocks of 8]
  const int b = blockIdx.z;
  const int m0 = blockIdx.y * 128;
  const int co0 = blockIdx.x * 128;
  const int tid = threadIdx.x;
  const int w = tid >> 6, l = tid & 63;
  const int wr = w >> 1, wc = w & 1;
  const int quad = l >> 4, l16 = l & 15;

  const float* Xb = x + (size_t)b * 512 * 1024;

  f32x4 acc[4][4];
#pragma unroll
  for (int i = 0; i < 4; ++i)
#pragma unroll
    for (int j = 0; j < 4; ++j) acc[i][j] = (f32x4){0.f, 0.f, 0.f, 0.f};

  const int nl = (tid & 31) * 4;   // n quad (coalesced loads)
  const int cp2 = (tid >> 5) * 2;  // c-pair base: c = cp2 + pp*16

  for (int kk = 0; kk < 8; ++kk) {
    const int k0 = kk * 64;
    f32x4 lo[4], hi[4];
#pragma unroll
    for (int pp = 0; pp < 4; ++pp) {
      const int c = cp2 + pp * 16;
      lo[pp] = *(const f32x4*)&Xb[(size_t)(k0 + c) * 1024 + m0 + nl];
      hi[pp] = *(const f32x4*)&Xb[(size_t)(k0 + c + 1) * 1024 + m0 + nl];
    }
    // packed b32 transposed writes
#pragma unroll
    for (int pp = 0; pp < 4; ++pp) {
      const int c = cp2 + pp * 16;
      const int blk = c >> 3, cin = c & 7;
#pragma unroll
      for (int i = 0; i < 4; ++i) {
        const int n = nl + i;
        bf16x2 pr;
        pr[0] = (bf16)lo[pp][i];
        pr[1] = (bf16)hi[pp][i];
        *(bf16x2*)&As[n * 72 + ((blk ^ swz(n)) << 3) + cin] = pr;
      }
    }
    __syncthreads();
#pragma unroll
    for (int ks = 0; ks < 2; ++ks) {
      bf16x8 a[4], bb[4];
#pragma unroll
      for (int rb = 0; rb < 4; ++rb) {
        const int m = wr * 64 + rb * 16 + l16;
        a[rb] = *(const bf16x8*)&As[m * 72 + (((ks * 4 + quad) ^ swz(m)) << 3)];
      }
#pragma unroll
      for (int cb = 0; cb < 4; ++cb)
        bb[cb] = *(const bf16x8*)&WqkvT[(size_t)(co0 + wc * 64 + cb * 16 + l16) * 512 +
                                        k0 + ks * 32 + quad * 8];
#pragma unroll
      for (int rb = 0; rb < 4; ++rb)
#pragma unroll
        for (int cb = 0; cb < 4; ++cb)
          acc[rb][cb] = __builtin_amdgcn_mfma_f32_16x16x32_bf16(a[rb], bb[cb], acc[rb][cb], 0, 0, 0);
    }
    __syncthreads();
  }

  // epilogue: co -> (head, part, d). part uniform within the 16-lane span.
#pragma unroll
  for (int cb = 0; cb < 4; ++cb) {
    const int co = co0 + wc * 64 + cb * 16 + l16;
    const int h = co / 192;
    const int rem = co - h * 192;
    const int part = rem >> 6;
    const int dd = rem & 63;
    const float bias = bqkv[co];
    if (part == 2) {  // V: d-major, vector store of 4 consecutive n
      bf16* base = Vb + ((size_t)(b * 8 + h) * 64 + dd) * 1024;
#pragma unroll
      for (int rb = 0; rb < 4; ++rb) {
        const int n = m0 + wr * 64 + rb * 16 + quad * 4;
        f32x4 v = acc[rb][cb];
        bf16x4 ov;
#pragma unroll
        for (int r = 0; r < 4; ++r) ov[r] = (bf16)(v[r] + bias);
        *(bf16x4*)&base[n] = ov;
      }
    } else {  // Q (pre-scaled by CEXP) / K: [bh][n][64]
      const float sc = (part == 0) ? CEXP : 1.0f;
      bf16* dst = (part == 0) ? Qb : Kb;
      bf16* base = dst + ((size_t)(b * 8 + h) * 1024) * 64 + dd;
#pragma unroll
      for (int rb = 0; rb < 4; ++rb) {
        const int n = m0 + wr * 64 + rb * 16 + quad * 4;
        f32x4 v = acc[rb][cb];
#pragma unroll
        for (int r = 0; r < 4; ++r) base[(size_t)(n + r) * 64] = (bf16)((v[r] + bias) * sc);
      }
    }
  }
}

// ---------------- flash attention v4 (round-9 known-good) ----------------
__global__ __launch_bounds__(256) void attn_k(const bf16* __restrict__ Qb,
                                              const bf16* __restrict__ Kb,
                                              const bf16* __restrict__ Vb,
                                              bf16* __restrict__ Ob) {
  __shared__ bf16 Ks[128 * 72];    // [j][d]
  __shared__ bf16 Vs[64 * 136];    // [d][j]
  __shared__ bf16 PQs[128 * 136];  // Q(stride 72) then P[m][j](stride 136)
  const int bh = blockIdx.x;       // bh fastest => head pinned per XCD
  const int b = bh >> 3, h = bh & 7;
  const int q0 = blockIdx.y * 128;
  const int tid = threadIdx.x;
  const int w = tid >> 6, l = tid & 63;
  const int quad = l >> 4, l16 = l & 15;

  const bf16* Qg = Qb + (size_t)bh * 1024 * 64;
  const bf16* Kg = Kb + (size_t)bh * 1024 * 64;
  const bf16* Vg = Vb + (size_t)bh * 64 * 1024;

  {  // stage Q tile 128x64 (pre-scaled): 32 elems/thread
    const int r = tid >> 1, c = (tid & 1) * 32;
#pragma unroll
    for (int e = 0; e < 4; ++e)
      *(bf16x8*)&PQs[r * 72 + c + e * 8] =
          *(const bf16x8*)&Qg[(size_t)(q0 + r) * 64 + c + e * 8];
  }
  __syncthreads();
  bf16x8 qb[8][2];  // hoisted Q B-frags: all 128 m rows
#pragma unroll
  for (int nb = 0; nb < 8; ++nb)
#pragma unroll
    for (int ks = 0; ks < 2; ++ks)
      qb[nb][ks] = *(const bf16x8*)&PQs[(nb * 16 + l16) * 72 + ks * 32 + quad * 8];

  bf16x8 ones;
#pragma unroll
  for (int e = 0; e < 8; ++e) ones[e] = (bf16)1.0f;

  f32x4 o[2][4], acc_l[2];
#pragma unroll
  for (int mt = 0; mt < 2; ++mt) {
    acc_l[mt] = (f32x4){0.f, 0.f, 0.f, 0.f};
#pragma unroll
    for (int db = 0; db < 4; ++db) o[mt][db] = (f32x4){0.f, 0.f, 0.f, 0.f};
  }

  const int kr = tid >> 1, kc = (tid & 1) * 32;  // K: 128j x 64d
  const int vr = tid >> 2, vc = (tid & 3) * 32;  // V: 64d x 128j

  bf16x8 ka[4], va[4];  // prefetch tile 0
#pragma unroll
  for (int e = 0; e < 4; ++e) {
    ka[e] = *(const bf16x8*)&Kg[(size_t)kr * 64 + kc + e * 8];
    va[e] = *(const bf16x8*)&Vg[(size_t)vr * 1024 + vc + e * 8];
  }

  for (int kv = 0; kv < 8; ++kv) {
    __syncthreads();  // prev PV reads done (iter0: Q-hoist done)
#pragma unroll
    for (int e = 0; e < 4; ++e) {
      *(bf16x8*)&Ks[kr * 72 + kc + e * 8] = ka[e];
      *(bf16x8*)&Vs[vr * 136 + vc + e * 8] = va[e];
    }
    __syncthreads();
    if (kv < 7) {  // prefetch next tile
      const int j0 = (kv + 1) * 128;
#pragma unroll
      for (int e = 0; e < 4; ++e) {
        ka[e] = *(const bf16x8*)&Kg[(size_t)(j0 + kr) * 64 + kc + e * 8];
        va[e] = *(const bf16x8*)&Vg[(size_t)vr * 1024 + j0 + vc + e * 8];
      }
    }

    // QK: wave w owns j in [w*32, w*32+32), all 128 m.
    f32x4 s[8][2];
#pragma unroll
    for (int nb = 0; nb < 8; ++nb)
#pragma unroll
      for (int jb = 0; jb < 2; ++jb) s[nb][jb] = (f32x4){0.f, 0.f, 0.f, 0.f};
#pragma unroll
    for (int ks = 0; ks < 2; ++ks) {
      bf16x8 kaf[2];
#pragma unroll
      for (int jb = 0; jb < 2; ++jb)
        kaf[jb] = *(const bf16x8*)&Ks[(w * 32 + jb * 16 + l16) * 72 + ks * 32 + quad * 8];
#pragma unroll
      for (int nb = 0; nb < 8; ++nb)
#pragma unroll
        for (int jb = 0; jb < 2; ++jb)
          s[nb][jb] = __builtin_amdgcn_mfma_f32_16x16x32_bf16(kaf[jb], qb[nb][ks], s[nb][jb], 0, 0, 0);
    }

    // P = exp2(S), packed b64 writes (4 consecutive j per lane)
#pragma unroll
    for (int nb = 0; nb < 8; ++nb)
#pragma unroll
      for (int jb = 0; jb < 2; ++jb) {
        bf16x4 pk;
#pragma unroll
        for (int rr = 0; rr < 4; ++rr) pk[rr] = (bf16)__builtin_amdgcn_exp2f(s[nb][jb][rr]);
        *(bf16x4*)&PQs[(nb * 16 + l16) * 136 + w * 32 + jb * 16 + quad * 4] = pk;
      }
    __syncthreads();  // P complete

    // PV: wave w owns m in [w*32, w*32+32), all 128 j.
#pragma unroll
    for (int kj = 0; kj < 4; ++kj) {
      bf16x8 ap[2];
#pragma unroll
      for (int mt = 0; mt < 2; ++mt) {
        ap[mt] = *(const bf16x8*)&PQs[(w * 32 + mt * 16 + l16) * 136 + kj * 32 + quad * 8];
        acc_l[mt] = __builtin_amdgcn_mfma_f32_16x16x32_bf16(ap[mt], ones, acc_l[mt], 0, 0, 0);
      }
#pragma unroll
      for (int db = 0; db < 4; ++db) {
        bf16x8 bv = *(const bf16x8*)&Vs[(db * 16 + l16) * 136 + kj * 32 + quad * 8];
#pragma unroll
        for (int mt = 0; mt < 2; ++mt)
          o[mt][db] = __builtin_amdgcn_mfma_f32_16x16x32_bf16(ap[mt], bv, o[mt][db], 0, 0, 0);
      }
    }
  }

  // epilogue: O /= l, write [b][n][h*64+d]
  bf16* Og = Ob + (size_t)b * 1024 * 512 + h * 64;
#pragma unroll
  for (int mt = 0; mt < 2; ++mt) {
    f32x4 inv;
#pragma unroll
    for (int rr = 0; rr < 4; ++rr) inv[rr] = 1.0f / acc_l[mt][rr];
#pragma unroll
    for (int db = 0; db < 4; ++db)
#pragma unroll
      for (int rr = 0; rr < 4; ++rr) {
        const int n = q0 + w * 32 + mt * 16 + quad * 4 + rr;
        Og[(size_t)n * 512 + db * 16 + l16] = (bf16)(o[mt][db][rr] * inv[rr]);
      }
  }
}

// ---------------- GEMM2: out = (O @ Wout + b + x)^T ----------------------
// NO LDS, NO barriers: A (Ob) and B (WoutT) frags direct from global/L2.
// Zero inter-thread communication -> cannot race.
__global__ __launch_bounds__(256) void gemm_out(const bf16* __restrict__ Ob,
                                                const bf16* __restrict__ WoutT,
                                                const float* __restrict__ bout,
                                                const float* __restrict__ x,
                                                float* __restrict__ out) {
  const int b = blockIdx.z;
  const int m0 = blockIdx.y * 128;
  const int co0 = blockIdx.x * 64;
  const int tid = threadIdx.x;
  const int w = tid >> 6, l = tid & 63;
  const int wr = w >> 1, wc = w & 1;
  const int quad = l >> 4, l16 = l & 15;

  const bf16* A = Ob + (size_t)b * 1024 * 512;

  f32x4 acc[4][2];
#pragma unroll
  for (int i = 0; i < 4; ++i)
#pragma unroll
    for (int j = 0; j < 2; ++j) acc[i][j] = (f32x4){0.f, 0.f, 0.f, 0.f};

  for (int kk = 0; kk < 16; ++kk) {
    const int k0 = kk * 32 + quad * 8;
    bf16x8 a[4], bb[2];
#pragma unroll
    for (int rb = 0; rb < 4; ++rb)
      a[rb] = *(const bf16x8*)&A[(size_t)(m0 + wr * 64 + rb * 16 + l16) * 512 + k0];
#pragma unroll
    for (int cb = 0; cb < 2; ++cb)
      bb[cb] = *(const bf16x8*)&WoutT[(size_t)(co0 + wc * 32 + cb * 16 + l16) * 512 + k0];
#pragma unroll
    for (int rb = 0; rb < 4; ++rb)
#pragma unroll
      for (int cb = 0; cb < 2; ++cb)
        acc[rb][cb] = __builtin_amdgcn_mfma_f32_16x16x32_bf16(a[rb], bb[cb], acc[rb][cb], 0, 0, 0);
  }

  // epilogue: D[n][c] + bias[c] + x[b][c][n] -> out[b][c][n] (fp32)
#pragma unroll
  for (int cb = 0; cb < 2; ++cb) {
    const int c = co0 + wc * 32 + cb * 16 + l16;
    const float bias = bout[c];
#pragma unroll
    for (int rb = 0; rb < 4; ++rb) {
      const int n = m0 + wr * 64 + rb * 16 + quad * 4;
      const size_t off = ((size_t)b * 512 + c) * 1024 + n;
      f32x4 res = *(const f32x4*)&x[off];
      f32x4 v = acc[rb][cb];
      f32x4 ov;
#pragma unroll
      for (int r = 0; r < 4; ++r) ov[r] = v[r] + bias + res[r];
      *(f32x4*)&out[off] = ov;
    }
  }
}

extern "C" void kernel_launch(void* const* d_in, const int* in_sizes, int n_in,
                              void* d_out, int out_size, void* d_ws, size_t ws_size,
                              hipStream_t stream) {
  const float* x = (const float*)d_in[0];     // [8][512][1024] fp32
  const float* Wqkv = (const float*)d_in[1];  // [512][1536]
  const float* bqkv = (const float*)d_in[2];  // [1536]
  const float* Wout = (const float*)d_in[3];  // [512][512]
  const float* bout = (const float*)d_in[4];  // [512]
  float* out = (float*)d_out;                 // [8][512][1024]
  char* ws = (char*)d_ws;

  const size_t MB = 1024 * 1024;
  bf16* Ob = (bf16*)(ws);             // 8 MB [8][1024][512]
  bf16* Qbuf = (bf16*)(ws + 8 * MB);  // 8 MB [64][1024][64] (pre-scaled)
  bf16* Kbuf = (bf16*)(ws + 16 * MB); // 8 MB [64][1024][64]
  bf16* Vbuf = (bf16*)(ws + 24 * MB); // 8 MB [64][64][1024] d-major
  bf16* WqkvT = (bf16*)(ws + 32 * MB);            // 1.5 MB [1536][512]
  bf16* WoutT = (bf16*)(ws + 32 * MB + 1572864);  // 0.5 MB [512][512]
  if (ws_size < 32 * MB + 1572864 + 524288) return;

  prep_k<<<dim3(48, 16, 2), dim3(32, 8), 0, stream>>>(Wqkv, Wout, WqkvT, WoutT);
  gemm_qkv<<<dim3(12, 8, 8), 256, 0, stream>>>(x, WqkvT, bqkv, Qbuf, Kbuf, Vbuf);
  attn_k<<<dim3(64, 8), 256, 0, stream>>>(Qbuf, Kbuf, Vbuf, Ob);
  gemm_out<<<dim3(8, 8, 8), 256, 0, stream>>>(Ob, WoutT, bout, x, out);
}

// Round 12
// 148.479 us; speedup vs baseline: 1.1967x; 1.1967x over previous
//
#include <hip/hip_runtime.h>
#include <hip/hip_bf16.h>
#include <cstdint>

typedef __bf16 bf16;
typedef __attribute__((ext_vector_type(8))) __bf16 bf16x8;
typedef __attribute__((ext_vector_type(4))) __bf16 bf16x4;
typedef __attribute__((ext_vector_type(4))) float f32x4;

#define CEXP 0.1803368801111244f  // (1/8) * log2(e), folded into Q

// ---------------- xpose: x fp32 [b][512c][1024n] -> xT bf16 [b][n][c] ----
__global__ __launch_bounds__(256) void xpose_k(const float* __restrict__ x,
                                               bf16* __restrict__ xT) {
  __shared__ bf16 t[32][33];
  const int b = blockIdx.z;
  const float* src = x + (size_t)b * 512 * 1024;
  bf16* dst = xT + (size_t)b * 1024 * 512;
  const int c0 = blockIdx.x * 32, r0 = blockIdx.y * 32;  // c0: n-tile, r0: c-tile
  const int tx = threadIdx.x, ty = threadIdx.y;
#pragma unroll
  for (int i = 0; i < 4; ++i)
    t[ty + i * 8][tx] = (bf16)src[(size_t)(r0 + ty + i * 8) * 1024 + c0 + tx];
  __syncthreads();
#pragma unroll
  for (int i = 0; i < 4; ++i)
    dst[(size_t)(c0 + ty + i * 8) * 512 + r0 + tx] = t[tx][ty + i * 8];
}

// ---------------- prep: weight transposes only ---------------------------
__global__ __launch_bounds__(256) void prep_k(const float* __restrict__ Wqkv,
                                              const float* __restrict__ Wout,
                                              bf16* __restrict__ WqkvT,
                                              bf16* __restrict__ WoutT) {
  __shared__ bf16 t[32][33];
  const int z = blockIdx.z;
  const float* src;
  bf16* dst;
  int R, C;
  if (z == 0) {
    src = Wqkv; dst = WqkvT; R = 512; C = 1536;
  } else {
    if (blockIdx.x >= 16) return;  // block-uniform exit (before any barrier)
    src = Wout; dst = WoutT; R = 512; C = 512;
  }
  const int c0 = blockIdx.x * 32, r0 = blockIdx.y * 32;
  const int tx = threadIdx.x, ty = threadIdx.y;
#pragma unroll
  for (int i = 0; i < 4; ++i)
    t[ty + i * 8][tx] = (bf16)src[(size_t)(r0 + ty + i * 8) * C + c0 + tx];
  __syncthreads();
#pragma unroll
  for (int i = 0; i < 4; ++i)
    dst[(size_t)(c0 + ty + i * 8) * R + r0 + tx] = t[tx][ty + i * 8];
}

// ---------------- GEMM1: qkv = xT @ Wqkv + b, scatter into Q/K/V --------
// bf16 xT, register-staged As+Bs (both LDS, stride 72), round-4 proven body
__global__ __launch_bounds__(256) void gemm_qkv(const bf16* __restrict__ xT,
                                                const bf16* __restrict__ WqkvT,
                                                const float* __restrict__ bqkv,
                                                bf16* __restrict__ Qb,
                                                bf16* __restrict__ Kb,
                                                bf16* __restrict__ Vb) {
  __shared__ bf16 As[128 * 72];
  __shared__ bf16 Bs[128 * 72];
  const int b = blockIdx.z;
  const int m0 = blockIdx.y * 128;
  const int co0 = blockIdx.x * 128;
  const int tid = threadIdx.x;
  const int w = tid >> 6, l = tid & 63;
  const int wr = w >> 1, wc = w & 1;
  const int quad = l >> 4, l16 = l & 15;

  const bf16* A = xT + (size_t)b * 1024 * 512;

  f32x4 acc[4][4];
#pragma unroll
  for (int i = 0; i < 4; ++i)
#pragma unroll
    for (int j = 0; j < 4; ++j) acc[i][j] = (f32x4){0.f, 0.f, 0.f, 0.f};

  const int srow = w * 32 + (l >> 3);
  const int scol = (l & 7) * 8;

  for (int kk = 0; kk < 8; ++kk) {
    const int k0 = kk * 64;
    bf16x8 av[4], bv[4];
#pragma unroll
    for (int i = 0; i < 4; ++i) {
      av[i] = *(const bf16x8*)&A[(size_t)(m0 + srow + i * 8) * 512 + k0 + scol];
      bv[i] = *(const bf16x8*)&WqkvT[(size_t)(co0 + srow + i * 8) * 512 + k0 + scol];
    }
#pragma unroll
    for (int i = 0; i < 4; ++i) {
      *(bf16x8*)&As[(srow + i * 8) * 72 + scol] = av[i];
      *(bf16x8*)&Bs[(srow + i * 8) * 72 + scol] = bv[i];
    }
    __syncthreads();
#pragma unroll
    for (int ks = 0; ks < 2; ++ks) {
      bf16x8 a[4], bb[4];
#pragma unroll
      for (int rb = 0; rb < 4; ++rb)
        a[rb] = *(const bf16x8*)&As[(wr * 64 + rb * 16 + l16) * 72 + ks * 32 + quad * 8];
#pragma unroll
      for (int cb = 0; cb < 4; ++cb)
        bb[cb] = *(const bf16x8*)&Bs[(wc * 64 + cb * 16 + l16) * 72 + ks * 32 + quad * 8];
#pragma unroll
      for (int rb = 0; rb < 4; ++rb)
#pragma unroll
        for (int cb = 0; cb < 4; ++cb)
          acc[rb][cb] = __builtin_amdgcn_mfma_f32_16x16x32_bf16(a[rb], bb[cb], acc[rb][cb], 0, 0, 0);
    }
    __syncthreads();
  }

  // epilogue: co -> (head, part, d). part uniform within the 16-lane span.
#pragma unroll
  for (int cb = 0; cb < 4; ++cb) {
    const int co = co0 + wc * 64 + cb * 16 + l16;
    const int h = co / 192;
    const int rem = co - h * 192;
    const int part = rem >> 6;
    const int dd = rem & 63;
    const float bias = bqkv[co];
    if (part == 2) {  // V: d-major, vector store of 4 consecutive n
      bf16* base = Vb + ((size_t)(b * 8 + h) * 64 + dd) * 1024;
#pragma unroll
      for (int rb = 0; rb < 4; ++rb) {
        const int n = m0 + wr * 64 + rb * 16 + quad * 4;
        f32x4 v = acc[rb][cb];
        bf16x4 ov;
#pragma unroll
        for (int r = 0; r < 4; ++r) ov[r] = (bf16)(v[r] + bias);
        *(bf16x4*)&base[n] = ov;
      }
    } else {  // Q (pre-scaled by CEXP) / K: [bh][n][64]
      const float sc = (part == 0) ? CEXP : 1.0f;
      bf16* dst = (part == 0) ? Qb : Kb;
      bf16* base = dst + ((size_t)(b * 8 + h) * 1024) * 64 + dd;
#pragma unroll
      for (int rb = 0; rb < 4; ++rb) {
        const int n = m0 + wr * 64 + rb * 16 + quad * 4;
        f32x4 v = acc[rb][cb];
#pragma unroll
        for (int r = 0; r < 4; ++r) base[(size_t)(n + r) * 64] = (bf16)((v[r] + bias) * sc);
      }
    }
  }
}

// ---------------- flash attention v4 (round-9 known-good) ----------------
__global__ __launch_bounds__(256) void attn_k(const bf16* __restrict__ Qb,
                                              const bf16* __restrict__ Kb,
                                              const bf16* __restrict__ Vb,
                                              bf16* __restrict__ Ob) {
  __shared__ bf16 Ks[128 * 72];    // [j][d]
  __shared__ bf16 Vs[64 * 136];    // [d][j]
  __shared__ bf16 PQs[128 * 136];  // Q(stride 72) then P[m][j](stride 136)
  const int bh = blockIdx.x;       // bh fastest => head pinned per XCD
  const int b = bh >> 3, h = bh & 7;
  const int q0 = blockIdx.y * 128;
  const int tid = threadIdx.x;
  const int w = tid >> 6, l = tid & 63;
  const int quad = l >> 4, l16 = l & 15;

  const bf16* Qg = Qb + (size_t)bh * 1024 * 64;
  const bf16* Kg = Kb + (size_t)bh * 1024 * 64;
  const bf16* Vg = Vb + (size_t)bh * 64 * 1024;

  {  // stage Q tile 128x64 (pre-scaled): 32 elems/thread
    const int r = tid >> 1, c = (tid & 1) * 32;
#pragma unroll
    for (int e = 0; e < 4; ++e)
      *(bf16x8*)&PQs[r * 72 + c + e * 8] =
          *(const bf16x8*)&Qg[(size_t)(q0 + r) * 64 + c + e * 8];
  }
  __syncthreads();
  bf16x8 qb[8][2];  // hoisted Q B-frags: all 128 m rows
#pragma unroll
  for (int nb = 0; nb < 8; ++nb)
#pragma unroll
    for (int ks = 0; ks < 2; ++ks)
      qb[nb][ks] = *(const bf16x8*)&PQs[(nb * 16 + l16) * 72 + ks * 32 + quad * 8];

  bf16x8 ones;
#pragma unroll
  for (int e = 0; e < 8; ++e) ones[e] = (bf16)1.0f;

  f32x4 o[2][4], acc_l[2];
#pragma unroll
  for (int mt = 0; mt < 2; ++mt) {
    acc_l[mt] = (f32x4){0.f, 0.f, 0.f, 0.f};
#pragma unroll
    for (int db = 0; db < 4; ++db) o[mt][db] = (f32x4){0.f, 0.f, 0.f, 0.f};
  }

  const int kr = tid >> 1, kc = (tid & 1) * 32;  // K: 128j x 64d
  const int vr = tid >> 2, vc = (tid & 3) * 32;  // V: 64d x 128j

  bf16x8 ka[4], va[4];  // prefetch tile 0
#pragma unroll
  for (int e = 0; e < 4; ++e) {
    ka[e] = *(const bf16x8*)&Kg[(size_t)kr * 64 + kc + e * 8];
    va[e] = *(const bf16x8*)&Vg[(size_t)vr * 1024 + vc + e * 8];
  }

  for (int kv = 0; kv < 8; ++kv) {
    __syncthreads();  // prev PV reads done (iter0: Q-hoist done)
#pragma unroll
    for (int e = 0; e < 4; ++e) {
      *(bf16x8*)&Ks[kr * 72 + kc + e * 8] = ka[e];
      *(bf16x8*)&Vs[vr * 136 + vc + e * 8] = va[e];
    }
    __syncthreads();
    if (kv < 7) {  // prefetch next tile
      const int j0 = (kv + 1) * 128;
#pragma unroll
      for (int e = 0; e < 4; ++e) {
        ka[e] = *(const bf16x8*)&Kg[(size_t)(j0 + kr) * 64 + kc + e * 8];
        va[e] = *(const bf16x8*)&Vg[(size_t)vr * 1024 + j0 + vc + e * 8];
      }
    }

    // QK: wave w owns j in [w*32, w*32+32), all 128 m.
    f32x4 s[8][2];
#pragma unroll
    for (int nb = 0; nb < 8; ++nb)
#pragma unroll
      for (int jb = 0; jb < 2; ++jb) s[nb][jb] = (f32x4){0.f, 0.f, 0.f, 0.f};
#pragma unroll
    for (int ks = 0; ks < 2; ++ks) {
      bf16x8 kaf[2];
#pragma unroll
      for (int jb = 0; jb < 2; ++jb)
        kaf[jb] = *(const bf16x8*)&Ks[(w * 32 + jb * 16 + l16) * 72 + ks * 32 + quad * 8];
#pragma unroll
      for (int nb = 0; nb < 8; ++nb)
#pragma unroll
        for (int jb = 0; jb < 2; ++jb)
          s[nb][jb] = __builtin_amdgcn_mfma_f32_16x16x32_bf16(kaf[jb], qb[nb][ks], s[nb][jb], 0, 0, 0);
    }

    // P = exp2(S), packed b64 writes (4 consecutive j per lane)
#pragma unroll
    for (int nb = 0; nb < 8; ++nb)
#pragma unroll
      for (int jb = 0; jb < 2; ++jb) {
        bf16x4 pk;
#pragma unroll
        for (int rr = 0; rr < 4; ++rr) pk[rr] = (bf16)__builtin_amdgcn_exp2f(s[nb][jb][rr]);
        *(bf16x4*)&PQs[(nb * 16 + l16) * 136 + w * 32 + jb * 16 + quad * 4] = pk;
      }
    __syncthreads();  // P complete

    // PV: wave w owns m in [w*32, w*32+32), all 128 j.
#pragma unroll
    for (int kj = 0; kj < 4; ++kj) {
      bf16x8 ap[2];
#pragma unroll
      for (int mt = 0; mt < 2; ++mt) {
        ap[mt] = *(const bf16x8*)&PQs[(w * 32 + mt * 16 + l16) * 136 + kj * 32 + quad * 8];
        acc_l[mt] = __builtin_amdgcn_mfma_f32_16x16x32_bf16(ap[mt], ones, acc_l[mt], 0, 0, 0);
      }
#pragma unroll
      for (int db = 0; db < 4; ++db) {
        bf16x8 bv = *(const bf16x8*)&Vs[(db * 16 + l16) * 136 + kj * 32 + quad * 8];
#pragma unroll
        for (int mt = 0; mt < 2; ++mt)
          o[mt][db] = __builtin_amdgcn_mfma_f32_16x16x32_bf16(ap[mt], bv, o[mt][db], 0, 0, 0);
      }
    }
  }

  // epilogue: O /= l, write [b][n][h*64+d]
  bf16* Og = Ob + (size_t)b * 1024 * 512 + h * 64;
#pragma unroll
  for (int mt = 0; mt < 2; ++mt) {
    f32x4 inv;
#pragma unroll
    for (int rr = 0; rr < 4; ++rr) inv[rr] = 1.0f / acc_l[mt][rr];
#pragma unroll
    for (int db = 0; db < 4; ++db)
#pragma unroll
      for (int rr = 0; rr < 4; ++rr) {
        const int n = q0 + w * 32 + mt * 16 + quad * 4 + rr;
        Og[(size_t)n * 512 + db * 16 + l16] = (bf16)(o[mt][db][rr] * inv[rr]);
      }
  }
}

// ---------------- GEMM2: out = (O @ Wout + b + x)^T (round-9 exact) ------
__global__ __launch_bounds__(256) void gemm_out(const bf16* __restrict__ Ob,
                                                const bf16* __restrict__ WoutT,
                                                const float* __restrict__ bout,
                                                const float* __restrict__ x,
                                                float* __restrict__ out) {
  __shared__ bf16 As[128 * 72];
  __shared__ bf16 Bs[64 * 72];
  const int b = blockIdx.z;
  const int m0 = blockIdx.y * 128;
  const int co0 = blockIdx.x * 64;
  const int tid = threadIdx.x;
  const int w = tid >> 6, l = tid & 63;
  const int wr = w >> 1, wc = w & 1;
  const int quad = l >> 4, l16 = l & 15;

  const bf16* A = Ob + (size_t)b * 1024 * 512;

  f32x4 acc[4][2];
#pragma unroll
  for (int i = 0; i < 4; ++i)
#pragma unroll
    for (int j = 0; j < 2; ++j) acc[i][j] = (f32x4){0.f, 0.f, 0.f, 0.f};

  const int srow = w * 32 + (l >> 3);  // A staging: 128 rows
  const int scol = (l & 7) * 8;
  const int brow = tid >> 2;           // B staging: 64 rows, 16 elems/thread
  const int bcol = (tid & 3) * 16;

  for (int kk = 0; kk < 8; ++kk) {
    const int k0 = kk * 64;
    bf16x8 av[4], bv[2];
#pragma unroll
    for (int i = 0; i < 4; ++i)
      av[i] = *(const bf16x8*)&A[(size_t)(m0 + srow + i * 8) * 512 + k0 + scol];
#pragma unroll
    for (int i = 0; i < 2; ++i)
      bv[i] = *(const bf16x8*)&WoutT[(size_t)(co0 + brow) * 512 + k0 + bcol + i * 8];
#pragma unroll
    for (int i = 0; i < 4; ++i)
      *(bf16x8*)&As[(srow + i * 8) * 72 + scol] = av[i];
#pragma unroll
    for (int i = 0; i < 2; ++i)
      *(bf16x8*)&Bs[brow * 72 + bcol + i * 8] = bv[i];
    __syncthreads();
#pragma unroll
    for (int ks = 0; ks < 2; ++ks) {
      bf16x8 a[4], bb[2];
#pragma unroll
      for (int rb = 0; rb < 4; ++rb)
        a[rb] = *(const bf16x8*)&As[(wr * 64 + rb * 16 + l16) * 72 + ks * 32 + quad * 8];
#pragma unroll
      for (int cb = 0; cb < 2; ++cb)
        bb[cb] = *(const bf16x8*)&Bs[(wc * 32 + cb * 16 + l16) * 72 + ks * 32 + quad * 8];
#pragma unroll
      for (int rb = 0; rb < 4; ++rb)
#pragma unroll
        for (int cb = 0; cb < 2; ++cb)
          acc[rb][cb] = __builtin_amdgcn_mfma_f32_16x16x32_bf16(a[rb], bb[cb], acc[rb][cb], 0, 0, 0);
    }
    __syncthreads();
  }

  // epilogue: D[n][c] + bias[c] + x[b][c][n] -> out[b][c][n] (fp32)
#pragma unroll
  for (int cb = 0; cb < 2; ++cb) {
    const int c = co0 + wc * 32 + cb * 16 + l16;
    const float bias = bout[c];
#pragma unroll
    for (int rb = 0; rb < 4; ++rb) {
      const int n = m0 + wr * 64 + rb * 16 + quad * 4;
      const size_t off = ((size_t)b * 512 + c) * 1024 + n;
      f32x4 res = *(const f32x4*)&x[off];
      f32x4 v = acc[rb][cb];
      f32x4 ov;
#pragma unroll
      for (int r = 0; r < 4; ++r) ov[r] = v[r] + bias + res[r];
      *(f32x4*)&out[off] = ov;
    }
  }
}

extern "C" void kernel_launch(void* const* d_in, const int* in_sizes, int n_in,
                              void* d_out, int out_size, void* d_ws, size_t ws_size,
                              hipStream_t stream) {
  const float* x = (const float*)d_in[0];     // [8][512][1024] fp32
  const float* Wqkv = (const float*)d_in[1];  // [512][1536]
  const float* bqkv = (const float*)d_in[2];  // [1536]
  const float* Wout = (const float*)d_in[3];  // [512][512]
  const float* bout = (const float*)d_in[4];  // [512]
  float* out = (float*)d_out;                 // [8][512][1024]
  char* ws = (char*)d_ws;

  const size_t MB = 1024 * 1024;
  bf16* xT = (bf16*)(ws);             // 8 MB [8][1024][512] bf16
  bf16* Ob = xT;                      // alias: xT dead after gemm_qkv
  bf16* Qbuf = (bf16*)(ws + 8 * MB);  // 8 MB [64][1024][64] (pre-scaled)
  bf16* Kbuf = (bf16*)(ws + 16 * MB); // 8 MB [64][1024][64]
  bf16* Vbuf = (bf16*)(ws + 24 * MB); // 8 MB [64][64][1024] d-major
  bf16* WqkvT = (bf16*)(ws + 32 * MB);            // 1.5 MB [1536][512]
  bf16* WoutT = (bf16*)(ws + 32 * MB + 1572864);  // 0.5 MB [512][512]
  if (ws_size < 32 * MB + 1572864 + 524288) return;

  xpose_k<<<dim3(32, 16, 8), dim3(32, 8), 0, stream>>>(x, xT);
  prep_k<<<dim3(48, 16, 2), dim3(32, 8), 0, stream>>>(Wqkv, Wout, WqkvT, WoutT);
  gemm_qkv<<<dim3(12, 8, 8), 256, 0, stream>>>(xT, WqkvT, bqkv, Qbuf, Kbuf, Vbuf);
  attn_k<<<dim3(64, 8), 256, 0, stream>>>(Qbuf, Kbuf, Vbuf, Ob);
  gemm_out<<<dim3(8, 8, 8), 256, 0, stream>>>(Ob, WoutT, bout, x, out);
}